// Round 1
// baseline (112.914 us; speedup 1.0000x reference)
//
#include <hip/hip_runtime.h>
#include <stdint.h>
#include <math.h>

// ---------------------------------------------------------------------------
// SubsetItems: reproduce JAX reference bit-exactly where it matters.
//   out[0:16384]      = idx   (8 x 2048) as float (values are small ints)
//   out[16384:32768]  = weight(8 x 2048) = min(j/204.8, 1)  (ranks==arange fwd)
// The only data-dependent output is idx = argsort(x_noised)[:, -2048:], which
// requires bit-exact threefry2x32 + XLA erf_inv f32 reproduction.
// ---------------------------------------------------------------------------

// JAX default flipped to partitionable threefry in jax 0.5.0. If this guess is
// wrong (absmax ~4e3 on idx), set to 0 for the legacy counter layout.
#define PARTITIONABLE 1

struct TF2 { uint32_t a, b; };

__host__ __device__ inline TF2 threefry2x32(uint32_t k0, uint32_t k1,
                                            uint32_t x0, uint32_t x1) {
  const uint32_t ks2 = k0 ^ k1 ^ 0x1BD11BDAu;
#define TF_ROT(v, d) (uint32_t)(((v) << (d)) | ((v) >> (32 - (d))))
#define TF_RND(r) do { x0 += x1; x1 = TF_ROT(x1, r); x1 ^= x0; } while (0)
  x0 += k0; x1 += k1;
  TF_RND(13); TF_RND(15); TF_RND(26); TF_RND(6);
  x0 += k1; x1 += ks2 + 1u;
  TF_RND(17); TF_RND(29); TF_RND(16); TF_RND(24);
  x0 += ks2; x1 += k0 + 2u;
  TF_RND(13); TF_RND(15); TF_RND(26); TF_RND(6);
  x0 += k0; x1 += k1 + 3u;
  TF_RND(17); TF_RND(29); TF_RND(16); TF_RND(24);
  x0 += k1; x1 += ks2 + 4u;
  TF_RND(13); TF_RND(15); TF_RND(26); TF_RND(6);
  x0 += ks2; x1 += k0 + 5u;
#undef TF_RND
#undef TF_ROT
  return {x0, x1};
}

// random_bits for a flat element index `idx` of an array with `half` = size/2.
__device__ __forceinline__ uint32_t random_bits_at(uint32_t ka, uint32_t kb,
                                                   uint32_t idx, uint32_t half) {
#if PARTITIONABLE
  TF2 r = threefry2x32(ka, kb, 0u, idx);   // iota_2x32: hi=0, lo=idx
  return r.a ^ r.b;
#else
  if (idx < half) { TF2 r = threefry2x32(ka, kb, idx, idx + half); return r.a; }
  else            { TF2 r = threefry2x32(ka, kb, idx - half, idx); return r.b; }
#endif
}

// XLA/CHLO ErfInv for f32 (Giles polynomial), with XLA's log1p select and a
// correctly-rounded f32 log (via double). __f*_rn defeat FMA contraction,
// which XLA never performs.
__device__ __forceinline__ float erfinv_f32_xla(float x) {
  float xx = __fmul_rn(x, x);
  float v  = -xx;                      // exact negation
  float w;
  if (fabsf(v) < 1e-4f) {              // XLA EmitLog1p small path
    float t = __fmul_rn(__fadd_rn(__fmul_rn(-0.5f, v), 1.0f), v);
    w = -t;
  } else {
    float t = __fadd_rn(v, 1.0f);      // f32 add, then log
    w = -(float)log((double)t);        // CR f32 log(t)
  }
  float p;
  if (w < 5.0f) {
    float ww = __fadd_rn(w, -2.5f);
    p = 2.81022636e-08f;
    p = __fadd_rn( 3.43273939e-07f, __fmul_rn(p, ww));
    p = __fadd_rn(-3.5233877e-06f,  __fmul_rn(p, ww));
    p = __fadd_rn(-4.39150654e-06f, __fmul_rn(p, ww));
    p = __fadd_rn( 0.00021858087f,  __fmul_rn(p, ww));
    p = __fadd_rn(-0.00125372503f,  __fmul_rn(p, ww));
    p = __fadd_rn(-0.00417768164f,  __fmul_rn(p, ww));
    p = __fadd_rn( 0.246640727f,    __fmul_rn(p, ww));
    p = __fadd_rn( 1.50140941f,     __fmul_rn(p, ww));
  } else {
    float ww = __fadd_rn(__fsqrt_rn(w), -3.0f);
    p = -0.000200214257f;
    p = __fadd_rn( 0.000100950558f, __fmul_rn(p, ww));
    p = __fadd_rn( 0.00134934322f,  __fmul_rn(p, ww));
    p = __fadd_rn(-0.00367342844f,  __fmul_rn(p, ww));
    p = __fadd_rn( 0.00573950773f,  __fmul_rn(p, ww));
    p = __fadd_rn(-0.0076224613f,   __fmul_rn(p, ww));
    p = __fadd_rn( 0.00943887047f,  __fmul_rn(p, ww));
    p = __fadd_rn( 1.00167406f,     __fmul_rn(p, ww));
    p = __fadd_rn( 2.83297682f,     __fmul_rn(p, ww));
  }
  return __fmul_rn(p, x);
}

// Kernel 1: per element, compute x_noised = clip(masked score) + noise.
__global__ __launch_bounds__(256)
void noise_kernel(const float* __restrict__ scores, float* __restrict__ xn,
                  uint32_t k1a, uint32_t k1b, uint32_t k2a, uint32_t k2b,
                  uint32_t k3a, uint32_t k3b) {
  int e = blockIdx.x * 256 + threadIdx.x;
  if (e >= 32768) return;
  int b = e >> 12;

  // mask = (uniform(k1) < 0.1) & (uniform(k2,(8,1)) < 0.75)
  uint32_t mbits = random_bits_at(k1a, k1b, (uint32_t)e, 16384u);
  uint32_t bbits = random_bits_at(k2a, k2b, (uint32_t)b, 4u);
  // u = (bits>>9)*2^-23;  u < 0.1f  <=> m <= 838860;  u < 0.75 <=> m < 6291456
  bool mask = ((mbits >> 9) <= 838860u) && ((bbits >> 9) < 6291456u);

  float s  = scores[e];
  float sf = scores[32767 - e];                 // flip over both axes
  float v  = mask ? fmaxf(s, sf) : s;
  float x  = fminf(fmaxf(v, -1.0f), 1.0f);      // clip

  // normal(k3): u = max(lo, floats*2 + lo); n = sqrt2f * erfinv(u)
  uint32_t nbits = random_bits_at(k3a, k3b, (uint32_t)e, 16384u);
  float f   = __uint_as_float((nbits >> 9) | 0x3f800000u);  // [1,2)
  float f01 = __fadd_rn(f, -1.0f);                          // exact, [0,1)
  const float lo = __uint_as_float(0xBF7FFFFFu);            // nextafter(-1,0)
  float u = __fadd_rn(__fmul_rn(f01, 2.0f), lo);            // hi-lo == 2.0f
  u = fmaxf(lo, u);
  float p    = erfinv_f32_xla(u);
  float nrm  = __fmul_rn(__uint_as_float(0x3FB504F3u), p);  // * float(sqrt(2))
  float nois = __fmul_rn(nrm, 0.0009765625f);               // * 2^-10 (exact)
  xn[e] = __fadd_rn(x, nois);
}

// Kernel 2: stable-ascending argsort via O(n) rank counting per element.
// Total-order key transform matches JAX's float->int sort trick (-0 < +0).
__global__ __launch_bounds__(256)
void rank_kernel(const float* __restrict__ xn, int* __restrict__ inv) {
  __shared__ uint32_t keys[4096];
  int b   = blockIdx.x >> 4;    // 8 rows x 16 blocks
  int blk = blockIdx.x & 15;
  const float* row = xn + b * 4096;
  for (int i = threadIdx.x; i < 4096; i += 256) {
    uint32_t ub = __float_as_uint(row[i]);
    keys[i] = (ub & 0x80000000u) ? ~ub : (ub | 0x80000000u);
  }
  __syncthreads();
  int i = blk * 256 + threadIdx.x;
  uint32_t ki = keys[i];
  int r = 0;
#pragma unroll 8
  for (int j = 0; j < 4096; ++j) {
    uint32_t kj = keys[j];
    r += (int)((kj < ki) || (kj == ki && j < i));   // stable tiebreak
  }
  inv[b * 4096 + r] = i;        // scatter: indexes[rank] = i
}

// Kernel 3: emit idx (as float) and weight.
__global__ __launch_bounds__(256)
void output_kernel(const int* __restrict__ inv, float* __restrict__ out) {
  int e = blockIdx.x * 256 + threadIdx.x;   // 16384
  if (e >= 16384) return;
  int b = e >> 11, j = e & 2047;
  out[e] = (float)inv[b * 4096 + 2048 + j];
  // ranks forward-value == arange -> weight = min(j/204.8, 1) (dev ~7e-7)
  out[16384 + e] = fminf(__fdiv_rn((float)j, 204.8f), 1.0f);
}

extern "C" void kernel_launch(void* const* d_in, const int* in_sizes, int n_in,
                              void* d_out, int out_size, void* d_ws, size_t ws_size,
                              hipStream_t stream) {
  const float* scores = (const float*)d_in[0];
  float* out = (float*)d_out;

  float* xn  = (float*)d_ws;                          // 32768 f32 = 128 KB
  int*   inv = (int*)((char*)d_ws + 32768 * 4);       // 32768 i32 = 128 KB

  // Derive k1,k2,k3 = split(key(42), 3) on host (pure integer math).
#if PARTITIONABLE
  TF2 K1 = threefry2x32(0u, 42u, 0u, 0u);
  TF2 K2 = threefry2x32(0u, 42u, 0u, 1u);
  TF2 K3 = threefry2x32(0u, 42u, 0u, 2u);
  uint32_t k1a = K1.a, k1b = K1.b;
  uint32_t k2a = K2.a, k2b = K2.b;
  uint32_t k3a = K3.a, k3b = K3.b;
#else
  TF2 b0 = threefry2x32(0u, 42u, 0u, 3u);
  TF2 b1 = threefry2x32(0u, 42u, 1u, 4u);
  TF2 b2 = threefry2x32(0u, 42u, 2u, 5u);
  uint32_t k1a = b0.a, k1b = b1.a;
  uint32_t k2a = b2.a, k2b = b0.b;
  uint32_t k3a = b1.b, k3b = b2.b;
#endif

  noise_kernel<<<128, 256, 0, stream>>>(scores, xn, k1a, k1b, k2a, k2b, k3a, k3b);
  rank_kernel<<<128, 256, 0, stream>>>(xn, inv);
  output_kernel<<<64, 256, 0, stream>>>(inv, out);
}

// Round 2
// 30.998 us; speedup vs baseline: 3.6426x; 3.6426x over previous
//
#include <hip/hip_runtime.h>
#include <stdint.h>
#include <math.h>

// ---------------------------------------------------------------------------
// SubsetItems, round 2: same bit-exact math as round 1 (absmax 0.0), but the
// O(n^2) rank phase restructured for parallelism:
//   k1: noise_kernel  -> packed 64-bit sort keys (total-order bits<<32 | col)
//   k2: rank_kernel   -> register-resident i-keys, j-split across blocks,
//                        partial rank counts to scratch (no atomics)
//   k3: finalize      -> sum partials; rank>=2048 scatters idx+weight directly
// ---------------------------------------------------------------------------

struct TF2 { uint32_t a, b; };

__host__ __device__ inline TF2 threefry2x32(uint32_t k0, uint32_t k1,
                                            uint32_t x0, uint32_t x1) {
  const uint32_t ks2 = k0 ^ k1 ^ 0x1BD11BDAu;
#define TF_ROT(v, d) (uint32_t)(((v) << (d)) | ((v) >> (32 - (d))))
#define TF_RND(r) do { x0 += x1; x1 = TF_ROT(x1, r); x1 ^= x0; } while (0)
  x0 += k0; x1 += k1;
  TF_RND(13); TF_RND(15); TF_RND(26); TF_RND(6);
  x0 += k1; x1 += ks2 + 1u;
  TF_RND(17); TF_RND(29); TF_RND(16); TF_RND(24);
  x0 += ks2; x1 += k0 + 2u;
  TF_RND(13); TF_RND(15); TF_RND(26); TF_RND(6);
  x0 += k0; x1 += k1 + 3u;
  TF_RND(17); TF_RND(29); TF_RND(16); TF_RND(24);
  x0 += k1; x1 += ks2 + 4u;
  TF_RND(13); TF_RND(15); TF_RND(26); TF_RND(6);
  x0 += ks2; x1 += k0 + 5u;
#undef TF_RND
#undef TF_ROT
  return {x0, x1};
}

// partitionable threefry random bits at flat index (verified bit-exact r1)
__host__ __device__ __forceinline__ uint32_t random_bits_at(uint32_t ka, uint32_t kb,
                                                            uint32_t idx) {
  TF2 r = threefry2x32(ka, kb, 0u, idx);
  return r.a ^ r.b;
}

// XLA/CHLO ErfInv f32 (verified bit-exact r1).
__device__ __forceinline__ float erfinv_f32_xla(float x) {
  float xx = __fmul_rn(x, x);
  float v  = -xx;
  float w;
  if (fabsf(v) < 1e-4f) {
    float t = __fmul_rn(__fadd_rn(__fmul_rn(-0.5f, v), 1.0f), v);
    w = -t;
  } else {
    float t = __fadd_rn(v, 1.0f);
    w = -(float)log((double)t);
  }
  float p;
  if (w < 5.0f) {
    float ww = __fadd_rn(w, -2.5f);
    p = 2.81022636e-08f;
    p = __fadd_rn( 3.43273939e-07f, __fmul_rn(p, ww));
    p = __fadd_rn(-3.5233877e-06f,  __fmul_rn(p, ww));
    p = __fadd_rn(-4.39150654e-06f, __fmul_rn(p, ww));
    p = __fadd_rn( 0.00021858087f,  __fmul_rn(p, ww));
    p = __fadd_rn(-0.00125372503f,  __fmul_rn(p, ww));
    p = __fadd_rn(-0.00417768164f,  __fmul_rn(p, ww));
    p = __fadd_rn( 0.246640727f,    __fmul_rn(p, ww));
    p = __fadd_rn( 1.50140941f,     __fmul_rn(p, ww));
  } else {
    float ww = __fadd_rn(__fsqrt_rn(w), -3.0f);
    p = -0.000200214257f;
    p = __fadd_rn( 0.000100950558f, __fmul_rn(p, ww));
    p = __fadd_rn( 0.00134934322f,  __fmul_rn(p, ww));
    p = __fadd_rn(-0.00367342844f,  __fmul_rn(p, ww));
    p = __fadd_rn( 0.00573950773f,  __fmul_rn(p, ww));
    p = __fadd_rn(-0.0076224613f,   __fmul_rn(p, ww));
    p = __fadd_rn( 0.00943887047f,  __fmul_rn(p, ww));
    p = __fadd_rn( 1.00167406f,     __fmul_rn(p, ww));
    p = __fadd_rn( 2.83297682f,     __fmul_rn(p, ww));
  }
  return __fmul_rn(p, x);
}

// Kernel 1: x_noised -> packed 64-bit total-order key. block=64, grid=512.
__global__ __launch_bounds__(64)
void noise_kernel(const float* __restrict__ scores, uint64_t* __restrict__ k64,
                  uint32_t k1a, uint32_t k1b, uint32_t k3a, uint32_t k3b,
                  uint32_t rowmask) {
  int e = blockIdx.x * 64 + threadIdx.x;   // 32768
  int b = e >> 12;

  uint32_t mbits = random_bits_at(k1a, k1b, (uint32_t)e);
  bool mask = ((mbits >> 9) <= 838860u) && ((rowmask >> b) & 1u);

  float s  = scores[e];
  float sf = scores[32767 - e];
  float v  = mask ? fmaxf(s, sf) : s;
  float x  = fminf(fmaxf(v, -1.0f), 1.0f);

  uint32_t nbits = random_bits_at(k3a, k3b, (uint32_t)e);
  float f   = __uint_as_float((nbits >> 9) | 0x3f800000u);
  float f01 = __fadd_rn(f, -1.0f);
  const float lo = __uint_as_float(0xBF7FFFFFu);
  float u = __fadd_rn(__fmul_rn(f01, 2.0f), lo);
  u = fmaxf(lo, u);
  float p    = erfinv_f32_xla(u);
  float nrm  = __fmul_rn(__uint_as_float(0x3FB504F3u), p);
  float nois = __fmul_rn(nrm, 0.0009765625f);
  float xnv  = __fadd_rn(x, nois);

  // total-order transform (-0 < +0, NaN ordering per XLA) + stable index
  uint32_t ub = __float_as_uint(xnv);
  uint32_t tk = (ub & 0x80000000u) ? ~ub : (ub | 0x80000000u);
  k64[e] = ((uint64_t)tk << 32) | (uint32_t)(e & 4095);
}

// Kernel 2: partial ranks. Block = (row, j-chunk). Each thread owns 16 i-keys
// in registers; j-key is wave-uniform (scalar load) amortized over 16 cmps.
#define IPT 16
__global__ __launch_bounds__(256)
void rank_kernel(const uint64_t* __restrict__ k64, int* __restrict__ partial,
                 int G, int jchunk) {
  int row = blockIdx.x / G;
  int g   = blockIdx.x - row * G;
  const uint64_t* rk = k64 + row * 4096;
  int t = threadIdx.x;

  uint64_t ki[IPT];
  int cnt[IPT];
#pragma unroll
  for (int m = 0; m < IPT; ++m) { ki[m] = rk[m * 256 + t]; cnt[m] = 0; }

  int j0 = g * jchunk, j1 = j0 + jchunk;
#pragma unroll 4
  for (int j = j0; j < j1; ++j) {
    uint64_t kj = rk[j];            // wave-uniform -> s_load, broadcast
#pragma unroll
    for (int m = 0; m < IPT; ++m) cnt[m] += (int)(kj < ki[m]);
  }

  int* pp = partial + (row * G + g) * 4096;
#pragma unroll
  for (int m = 0; m < IPT; ++m) pp[m * 256 + t] = cnt[m];
}

// Kernel 3: rank = sum of partials; rank>=2048 -> emit idx + weight directly.
__global__ __launch_bounds__(256)
void finalize_kernel(const int* __restrict__ partial, float* __restrict__ out,
                     int G) {
  int e = blockIdx.x * 256 + threadIdx.x;  // 32768
  int row = e >> 12, i = e & 4095;
  const int* pp = partial + row * G * 4096 + i;
  int r = 0;
  for (int g = 0; g < G; ++g) r += pp[g * 4096];
  if (r >= 2048) {
    int j = r - 2048;
    out[row * 2048 + j] = (float)i;
    out[16384 + row * 2048 + j] = fminf(__fdiv_rn((float)j, 204.8f), 1.0f);
  }
}

extern "C" void kernel_launch(void* const* d_in, const int* in_sizes, int n_in,
                              void* d_out, int out_size, void* d_ws, size_t ws_size,
                              hipStream_t stream) {
  const float* scores = (const float*)d_in[0];
  float* out = (float*)d_out;

  uint64_t* k64     = (uint64_t*)d_ws;                    // 256 KB
  int*      partial = (int*)((char*)d_ws + 32768 * 8);

  // split(key(42), 3), partitionable layout (verified r1)
  TF2 K1 = threefry2x32(0u, 42u, 0u, 0u);
  TF2 K2 = threefry2x32(0u, 42u, 0u, 1u);
  TF2 K3 = threefry2x32(0u, 42u, 0u, 2u);

  // batch_mask rows on host: uniform(k2,(8,1)) < 0.75
  uint32_t rowmask = 0;
  for (uint32_t b = 0; b < 8; ++b) {
    uint32_t bits = random_bits_at(K2.a, K2.b, b);
    if ((bits >> 9) < 6291456u) rowmask |= (1u << b);
  }

  // pick largest j-split G whose partial matrix fits the workspace
  int G = 32;
  while (G > 1 && (size_t)(32768u * 8u) + (size_t)(8 * G * 4096) * 4u > ws_size)
    G >>= 1;
  int jchunk = 4096 / G;

  noise_kernel<<<512, 64, 0, stream>>>(scores, k64, K1.a, K1.b, K3.a, K3.b, rowmask);
  rank_kernel<<<8 * G, 256, 0, stream>>>(k64, partial, G, jchunk);
  finalize_kernel<<<128, 256, 0, stream>>>(partial, out, G);
}

// Round 3
// 28.180 us; speedup vs baseline: 4.0069x; 1.1000x over previous
//
#include <hip/hip_runtime.h>
#include <stdint.h>
#include <math.h>

// ---------------------------------------------------------------------------
// SubsetItems, round 3: same bit-exact math (absmax 0.0 in r1/r2).
// Change vs r2: rank j-split G 32->64 (512 blocks = 2 waves/SIMD so carry-reg
// serialization in the u64 cmp+addc chains hides under a second wave),
// finalize unrolled. 3 kernels:
//   k1 noise    -> packed 64-bit total-order keys (tk<<32 | col)
//   k2 rank     -> partial rank counts, register-resident i-keys
//   k3 finalize -> sum 64 partials; rank>=2048 scatters idx+weight
// ---------------------------------------------------------------------------

#define RANK_G   64
#define JCHUNK   (4096 / RANK_G)
#define IPT      16

struct TF2 { uint32_t a, b; };

__host__ __device__ inline TF2 threefry2x32(uint32_t k0, uint32_t k1,
                                            uint32_t x0, uint32_t x1) {
  const uint32_t ks2 = k0 ^ k1 ^ 0x1BD11BDAu;
#define TF_ROT(v, d) (uint32_t)(((v) << (d)) | ((v) >> (32 - (d))))
#define TF_RND(r) do { x0 += x1; x1 = TF_ROT(x1, r); x1 ^= x0; } while (0)
  x0 += k0; x1 += k1;
  TF_RND(13); TF_RND(15); TF_RND(26); TF_RND(6);
  x0 += k1; x1 += ks2 + 1u;
  TF_RND(17); TF_RND(29); TF_RND(16); TF_RND(24);
  x0 += ks2; x1 += k0 + 2u;
  TF_RND(13); TF_RND(15); TF_RND(26); TF_RND(6);
  x0 += k0; x1 += k1 + 3u;
  TF_RND(17); TF_RND(29); TF_RND(16); TF_RND(24);
  x0 += k1; x1 += ks2 + 4u;
  TF_RND(13); TF_RND(15); TF_RND(26); TF_RND(6);
  x0 += ks2; x1 += k0 + 5u;
#undef TF_RND
#undef TF_ROT
  return {x0, x1};
}

// partitionable threefry random bits at flat index (bit-exact, verified r1)
__host__ __device__ __forceinline__ uint32_t random_bits_at(uint32_t ka, uint32_t kb,
                                                            uint32_t idx) {
  TF2 r = threefry2x32(ka, kb, 0u, idx);
  return r.a ^ r.b;
}

// XLA/CHLO ErfInv f32 (bit-exact, verified r1).
__device__ __forceinline__ float erfinv_f32_xla(float x) {
  float xx = __fmul_rn(x, x);
  float v  = -xx;
  float w;
  if (fabsf(v) < 1e-4f) {
    float t = __fmul_rn(__fadd_rn(__fmul_rn(-0.5f, v), 1.0f), v);
    w = -t;
  } else {
    float t = __fadd_rn(v, 1.0f);
    w = -(float)log((double)t);
  }
  float p;
  if (w < 5.0f) {
    float ww = __fadd_rn(w, -2.5f);
    p = 2.81022636e-08f;
    p = __fadd_rn( 3.43273939e-07f, __fmul_rn(p, ww));
    p = __fadd_rn(-3.5233877e-06f,  __fmul_rn(p, ww));
    p = __fadd_rn(-4.39150654e-06f, __fmul_rn(p, ww));
    p = __fadd_rn( 0.00021858087f,  __fmul_rn(p, ww));
    p = __fadd_rn(-0.00125372503f,  __fmul_rn(p, ww));
    p = __fadd_rn(-0.00417768164f,  __fmul_rn(p, ww));
    p = __fadd_rn( 0.246640727f,    __fmul_rn(p, ww));
    p = __fadd_rn( 1.50140941f,     __fmul_rn(p, ww));
  } else {
    float ww = __fadd_rn(__fsqrt_rn(w), -3.0f);
    p = -0.000200214257f;
    p = __fadd_rn( 0.000100950558f, __fmul_rn(p, ww));
    p = __fadd_rn( 0.00134934322f,  __fmul_rn(p, ww));
    p = __fadd_rn(-0.00367342844f,  __fmul_rn(p, ww));
    p = __fadd_rn( 0.00573950773f,  __fmul_rn(p, ww));
    p = __fadd_rn(-0.0076224613f,   __fmul_rn(p, ww));
    p = __fadd_rn( 0.00943887047f,  __fmul_rn(p, ww));
    p = __fadd_rn( 1.00167406f,     __fmul_rn(p, ww));
    p = __fadd_rn( 2.83297682f,     __fmul_rn(p, ww));
  }
  return __fmul_rn(p, x);
}

// Kernel 1: x_noised -> packed 64-bit total-order key.
__global__ __launch_bounds__(64)
void noise_kernel(const float* __restrict__ scores, uint64_t* __restrict__ k64,
                  uint32_t k1a, uint32_t k1b, uint32_t k3a, uint32_t k3b,
                  uint32_t rowmask) {
  int e = blockIdx.x * 64 + threadIdx.x;   // 32768
  int b = e >> 12;

  uint32_t mbits = random_bits_at(k1a, k1b, (uint32_t)e);
  bool mask = ((mbits >> 9) <= 838860u) && ((rowmask >> b) & 1u);

  float s  = scores[e];
  float sf = scores[32767 - e];
  float v  = mask ? fmaxf(s, sf) : s;
  float x  = fminf(fmaxf(v, -1.0f), 1.0f);

  uint32_t nbits = random_bits_at(k3a, k3b, (uint32_t)e);
  float f   = __uint_as_float((nbits >> 9) | 0x3f800000u);
  float f01 = __fadd_rn(f, -1.0f);
  const float lo = __uint_as_float(0xBF7FFFFFu);
  float u = __fadd_rn(__fmul_rn(f01, 2.0f), lo);
  u = fmaxf(lo, u);
  float p    = erfinv_f32_xla(u);
  float nrm  = __fmul_rn(__uint_as_float(0x3FB504F3u), p);
  float nois = __fmul_rn(nrm, 0.0009765625f);
  float xnv  = __fadd_rn(x, nois);

  uint32_t ub = __float_as_uint(xnv);
  uint32_t tk = (ub & 0x80000000u) ? ~ub : (ub | 0x80000000u);
  k64[e] = ((uint64_t)tk << 32) | (uint32_t)(e & 4095);
}

// Kernel 2: partial ranks. Block = (row, j-chunk); 512 blocks = 2 waves/SIMD.
__global__ __launch_bounds__(256)
void rank_kernel(const uint64_t* __restrict__ k64, int* __restrict__ partial) {
  int row = blockIdx.x >> 6;              // /RANK_G
  int g   = blockIdx.x & (RANK_G - 1);
  const uint64_t* rk = k64 + row * 4096;
  int t = threadIdx.x;

  uint64_t ki[IPT];
  int cnt[IPT];
#pragma unroll
  for (int m = 0; m < IPT; ++m) { ki[m] = rk[m * 256 + t]; cnt[m] = 0; }

  int j0 = g * JCHUNK;
#pragma unroll 4
  for (int j = j0; j < j0 + JCHUNK; ++j) {
    uint64_t kj = rk[j];                  // wave-uniform -> scalar load
#pragma unroll
    for (int m = 0; m < IPT; ++m) cnt[m] += (int)(kj < ki[m]);
  }

  int* pp = partial + (row * RANK_G + g) * 4096;
#pragma unroll
  for (int m = 0; m < IPT; ++m) pp[m * 256 + t] = cnt[m];
}

// Kernel 3: rank = sum of partials; rank>=2048 -> emit idx + weight.
__global__ __launch_bounds__(256)
void finalize_kernel(const int* __restrict__ partial, float* __restrict__ out) {
  int e = blockIdx.x * 256 + threadIdx.x;  // 32768
  int row = e >> 12, i = e & 4095;
  const int* pp = partial + row * RANK_G * 4096 + i;
  int r = 0;
#pragma unroll 8
  for (int g = 0; g < RANK_G; ++g) r += pp[g * 4096];
  if (r >= 2048) {
    int j = r - 2048;
    out[row * 2048 + j] = (float)i;
    out[16384 + row * 2048 + j] = fminf(__fdiv_rn((float)j, 204.8f), 1.0f);
  }
}

extern "C" void kernel_launch(void* const* d_in, const int* in_sizes, int n_in,
                              void* d_out, int out_size, void* d_ws, size_t ws_size,
                              hipStream_t stream) {
  const float* scores = (const float*)d_in[0];
  float* out = (float*)d_out;

  uint64_t* k64     = (uint64_t*)d_ws;                 // 256 KB
  int*      partial = (int*)((char*)d_ws + 32768 * 8); // 8 MB (ws is 256 MB)

  // split(key(42), 3), partitionable layout (verified r1)
  TF2 K1 = threefry2x32(0u, 42u, 0u, 0u);
  TF2 K2 = threefry2x32(0u, 42u, 0u, 1u);
  TF2 K3 = threefry2x32(0u, 42u, 0u, 2u);

  // batch_mask rows on host: uniform(k2,(8,1)) < 0.75
  uint32_t rowmask = 0;
  for (uint32_t b = 0; b < 8; ++b) {
    uint32_t bits = random_bits_at(K2.a, K2.b, b);
    if ((bits >> 9) < 6291456u) rowmask |= (1u << b);
  }

  noise_kernel<<<512, 64, 0, stream>>>(scores, k64, K1.a, K1.b, K3.a, K3.b, rowmask);
  rank_kernel<<<8 * RANK_G, 256, 0, stream>>>(k64, partial);
  finalize_kernel<<<128, 256, 0, stream>>>(partial, out);
}